// Round 2
// baseline (350.626 us; speedup 1.0000x reference)
//
#include <hip/hip_runtime.h>
#include <hip/hip_bf16.h>
#include <math.h>

typedef __attribute__((ext_vector_type(8))) short bf16x8;
typedef __attribute__((ext_vector_type(4))) float f32x4;

constexpr int Bn = 64;    // batch (dialogues)
constexpr int Ln = 512;   // utterances
constexpr int Hd = 768;   // hidden
constexpr int Nn = 50;    // nodes per dialogue
constexpr int On = 768;   // output dim

// ---------------------------------------------------------------------------
// Decide whether float tensors are stored as f32 (flag=1) or bf16 (flag=0).
// For bf16-pair data, the low 16 bits of each 32-bit word are a bf16 normal
// value -> exponent field in [110,135] ~100% of the time. For f32 data the
// low 16 bits are mantissa bits -> ~10%. Count over 1024 words of emb.
__global__ __launch_bounds__(256) void sniff_kernel(
    const unsigned int* __restrict__ emb_raw, int* __restrict__ flag) {
  __shared__ int cnt;
  if (threadIdx.x == 0) cnt = 0;
  __syncthreads();
  int c = 0;
  for (int i = threadIdx.x; i < 1024; i += 256) {
    unsigned int lo = emb_raw[i] & 0xFFFFu;
    unsigned int e = (lo >> 7) & 0xFFu;
    if (e >= 110 && e <= 135) c++;
  }
  atomicAdd(&cnt, c);
  __syncthreads();
  if (threadIdx.x == 0) flag[0] = (cnt > 512) ? 0 : 1;  // 0=bf16, 1=f32
}

// ---------------------------------------------------------------------------
// Canonicalize all float param tensors into internal bf16 buffers.
struct CvtJob { const void* src; __hip_bfloat16* dst; int n; int pad; };
struct CvtJobs { CvtJob j[13]; };

__global__ __launch_bounds__(256) void cvt_kernel(CvtJobs jobs,
                                                  const int* __restrict__ flag) {
  const int f = flag[0];
  const CvtJob J = jobs.j[blockIdx.y];
  int idx = blockIdx.x * 256 + threadIdx.x;
  int stride = gridDim.x * 256;
  if (f) {
    const float* s = (const float*)J.src;
    for (int i = idx; i < J.n; i += stride) J.dst[i] = __float2bfloat16(s[i]);
  } else {
    const __hip_bfloat16* s = (const __hip_bfloat16*)J.src;
    for (int i = idx; i < J.n; i += stride) J.dst[i] = s[i];
  }
}

// ---------------------------------------------------------------------------
// Transpose Hd x Hd bf16: Wt[n][k] = W[k][n]
__global__ __launch_bounds__(256) void transpose_kernel(
    const __hip_bfloat16* __restrict__ W, __hip_bfloat16* __restrict__ Wt) {
  __shared__ __hip_bfloat16 tile[32][33];
  int bx = blockIdx.x * 32;  // k offset
  int by = blockIdx.y * 32;  // n offset
  int c = threadIdx.x & 31, r0 = threadIdx.x >> 5;
  for (int r = r0; r < 32; r += 8)
    tile[r][c] = W[(size_t)(bx + r) * Hd + by + c];
  __syncthreads();
  for (int r = r0; r < 32; r += 8)
    Wt[(size_t)(by + r) * Hd + bx + c] = tile[c][r];
}

// ---------------------------------------------------------------------------
// Gather CLS rows + sinusoidal PE -> x (f32) and x (bf16). Dual-dtype read.
__global__ __launch_bounds__(256) void gather_pe_kernel(
    const void* __restrict__ emb, const int* __restrict__ ids,
    const int* __restrict__ flag, float* __restrict__ xf,
    __hip_bfloat16* __restrict__ xb) {
  const int f = flag[0];
  int bn = blockIdx.x;              // b*Nn + n
  int b = bn / Nn, n = bn % Nn;
  int id = ids[bn];
  size_t base = ((size_t)b * Ln + id) * Hd;
  float* xo = xf + (size_t)bn * Hd;
  __hip_bfloat16* xbo = xb + (size_t)bn * Hd;
  const float kLog = 9.210340371976184f / (float)Hd;  // ln(10000)/H
  for (int h = threadIdx.x; h < Hd; h += 256) {
    int he = h & ~1;
    float freq = expf(-(float)he * kLog);
    float ang = (float)n * freq;
    float pe = (h & 1) ? cosf(ang) : sinf(ang);
    float ev = f ? ((const float*)emb)[base + h]
                 : __bfloat162float(((const __hip_bfloat16*)emb)[base + h]);
    float v = ev + pe;
    xo[h] = v;
    xbo[h] = __float2bfloat16(v);
  }
}

// ---------------------------------------------------------------------------
// C[M,768] = A[M,768] @ Bt[768,768]^T + bias   (Bt[n][k] = W[k][n])
// MODE 0: none, MODE 1: tanh
template <int MODE>
__global__ __launch_bounds__(256) void gemm_bt_kernel(
    const __hip_bfloat16* __restrict__ A, const __hip_bfloat16* __restrict__ Bt,
    const __hip_bfloat16* __restrict__ bias, float* __restrict__ C) {
  __shared__ __hip_bfloat16 As[64][40];  // pad to 40 (80B rows, 16B aligned)
  __shared__ __hip_bfloat16 Bs[64][40];
  int tid = threadIdx.x;
  int wave = tid >> 6, lane = tid & 63;
  int lr = lane & 15, lq = lane >> 4;
  int row0 = blockIdx.x * 64, col0 = blockIdx.y * 64;
  int sr = tid >> 2, sk = (tid & 3) * 8;
  const __hip_bfloat16* Ap = A + (size_t)(row0 + sr) * Hd + sk;
  const __hip_bfloat16* Bp = Bt + (size_t)(col0 + sr) * Hd + sk;
  f32x4 acc[4] = {};
  for (int kt = 0; kt < Hd; kt += 32) {
    *(uint4*)&As[sr][sk] = *(const uint4*)(Ap + kt);
    *(uint4*)&Bs[sr][sk] = *(const uint4*)(Bp + kt);
    __syncthreads();
    bf16x8 af = *(const bf16x8*)&As[wave * 16 + lr][lq * 8];
#pragma unroll
    for (int ct = 0; ct < 4; ++ct) {
      bf16x8 bfrag = *(const bf16x8*)&Bs[ct * 16 + lr][lq * 8];
      acc[ct] = __builtin_amdgcn_mfma_f32_16x16x32_bf16(af, bfrag, acc[ct], 0, 0, 0);
    }
    __syncthreads();
  }
  int cr0 = row0 + wave * 16 + lq * 4;
#pragma unroll
  for (int ct = 0; ct < 4; ++ct) {
    int gc = col0 + ct * 16 + lr;
    float bv = __bfloat162float(bias[gc]);
#pragma unroll
    for (int r = 0; r < 4; ++r) {
      float v = acc[ct][r] + bv;
      if (MODE == 1) v = tanhf(v);
      C[(size_t)(cr0 + r) * Hd + gc] = v;
    }
  }
}

// ---------------------------------------------------------------------------
// Per-row dots with a[:H] and a[H:]
__global__ __launch_bounds__(256) void srcdst_kernel(
    const float* __restrict__ Wh, const __hip_bfloat16* __restrict__ a,
    float* __restrict__ ssrc, float* __restrict__ sdst) {
  int row = blockIdx.x;
  const float* w = Wh + (size_t)row * Hd;
  float s1 = 0.f, s2 = 0.f;
  for (int h = threadIdx.x; h < Hd; h += 256) {
    float wv = w[h];
    s1 += wv * __bfloat162float(a[h]);
    s2 += wv * __bfloat162float(a[Hd + h]);
  }
#pragma unroll
  for (int off = 32; off; off >>= 1) {
    s1 += __shfl_down(s1, off);
    s2 += __shfl_down(s2, off);
  }
  __shared__ float r1[4], r2[4];
  int wv_ = threadIdx.x >> 6;
  if ((threadIdx.x & 63) == 0) { r1[wv_] = s1; r2[wv_] = s2; }
  __syncthreads();
  if (threadIdx.x == 0) {
    ssrc[row] = r1[0] + r1[1] + r1[2] + r1[3];
    sdst[row] = r2[0] + r2[1] + r2[2] + r2[3];
  }
}

// ---------------------------------------------------------------------------
// att[b,i,:] = softmax_j( mask(adj, leaky_relu(s_src[i]+s_dst[j]+ab)) )
__global__ __launch_bounds__(64) void att_kernel(
    const float* __restrict__ ssrc, const float* __restrict__ sdst,
    const int* __restrict__ adj, const __hip_bfloat16* __restrict__ ab,
    float* __restrict__ att) {
  int bi = blockIdx.x;   // b*Nn + i
  int b = bi / Nn;
  int j = threadIdx.x;
  bool valid = j < Nn;
  float abv = __bfloat162float(ab[0]);
  float e = -3.0e38f;
  if (valid) {
    float t = ssrc[bi] + sdst[b * Nn + j] + abv;
    t = t > 0.f ? t : 0.3f * t;           // leaky_relu alpha=0.3
    e = (adj[(size_t)bi * Nn + j] > 0) ? t : -9.0e15f;
  }
  float m = e;
#pragma unroll
  for (int off = 32; off; off >>= 1) m = fmaxf(m, __shfl_xor(m, off));
  float p = valid ? expf(e - m) : 0.f;
  float s = p;
#pragma unroll
  for (int off = 32; off; off >>= 1) s += __shfl_xor(s, off);
  if (valid) att[(size_t)bi * Nn + j] = p / s;
}

// ---------------------------------------------------------------------------
// h[bi,:] = elu(att[bi,:] @ Wh[b]) (+ x residual for LAYER 2); bf16 (+f32) out
template <int LAYER>
__global__ __launch_bounds__(256) void attwh_kernel(
    const float* __restrict__ att, const float* __restrict__ Wh,
    const float* __restrict__ xres, float* __restrict__ hf,
    __hip_bfloat16* __restrict__ hb) {
  int bi = blockIdx.x;
  int b = bi / Nn;
  __shared__ float as_[Nn];
  if (threadIdx.x < Nn) as_[threadIdx.x] = att[(size_t)bi * Nn + threadIdx.x];
  __syncthreads();
  const float* Whb = Wh + (size_t)b * Nn * Hd;
  for (int h = threadIdx.x; h < Hd; h += 256) {
    float acc = 0.f;
#pragma unroll 10
    for (int j = 0; j < Nn; ++j) acc += as_[j] * Whb[(size_t)j * Hd + h];
    float v = acc > 0.f ? acc : (expf(acc) - 1.0f);  // elu
    if (LAYER == 2) {
      v += xres[(size_t)bi * Hd + h];
      hf[(size_t)bi * Hd + h] = v;
    }
    hb[(size_t)bi * Hd + h] = __float2bfloat16(v);
  }
}

// ---------------------------------------------------------------------------
// sraw[row] = T[row,:] . v
__global__ __launch_bounds__(64) void dotv_kernel(
    const float* __restrict__ T, const __hip_bfloat16* __restrict__ v,
    float* __restrict__ out) {
  int row = blockIdx.x;
  float s = 0.f;
  for (int h = threadIdx.x; h < Hd; h += 64)
    s += T[(size_t)row * Hd + h] * __bfloat162float(v[h]);
#pragma unroll
  for (int off = 32; off; off >>= 1) s += __shfl_xor(s, off);
  if (threadIdx.x == 0) out[row] = s;
}

// ---------------------------------------------------------------------------
// d[b,:] = softmax_n(sraw[b,:]) @ h2[b]   (bf16 out, internal)
__global__ __launch_bounds__(256) void pool_kernel(
    const float* __restrict__ sraw, const float* __restrict__ h2,
    __hip_bfloat16* __restrict__ d) {
  int b = blockIdx.x;
  __shared__ float sc[Nn];
  if (threadIdx.x < 64) {
    int j = threadIdx.x;
    float e = (j < Nn) ? sraw[b * Nn + j] : -3.0e38f;
    float m = e;
#pragma unroll
    for (int off = 32; off; off >>= 1) m = fmaxf(m, __shfl_xor(m, off));
    float p = (j < Nn) ? expf(e - m) : 0.f;
    float s = p;
#pragma unroll
    for (int off = 32; off; off >>= 1) s += __shfl_xor(s, off);
    if (j < Nn) sc[j] = p / s;
  }
  __syncthreads();
  const float* hbase = h2 + (size_t)b * Nn * Hd;
  for (int h = threadIdx.x; h < Hd; h += 256) {
    float acc = 0.f;
#pragma unroll 10
    for (int j = 0; j < Nn; ++j) acc += sc[j] * hbase[(size_t)j * Hd + h];
    d[(size_t)b * Hd + h] = __float2bfloat16(acc);
  }
}

// ---------------------------------------------------------------------------
// out[b,o] = d[b,:] . Wl[:,o] + bl[o]   (dual-dtype output per flag)
__global__ __launch_bounds__(256) void final_kernel(
    const __hip_bfloat16* __restrict__ d, const __hip_bfloat16* __restrict__ Wl,
    const __hip_bfloat16* __restrict__ bl, const int* __restrict__ flag,
    void* __restrict__ out) {
  const int f = flag[0];
  int b = blockIdx.x;
  int o = blockIdx.y * 256 + threadIdx.x;
  __shared__ float ds[Hd];
  for (int h = threadIdx.x; h < Hd; h += 256)
    ds[h] = __bfloat162float(d[(size_t)b * Hd + h]);
  __syncthreads();
  float acc = __bfloat162float(bl[o]);
  for (int h = 0; h < Hd; ++h)
    acc += ds[h] * __bfloat162float(Wl[(size_t)h * On + o]);
  size_t oi = (size_t)b * On + o;
  if (f) ((float*)out)[oi] = acc;
  else ((__hip_bfloat16*)out)[oi] = __float2bfloat16(acc);
}

// ---------------------------------------------------------------------------
extern "C" void kernel_launch(void* const* d_in, const int* in_sizes, int n_in,
                              void* d_out, int out_size, void* d_ws, size_t ws_size,
                              hipStream_t stream) {
  const void* emb = d_in[0];
  const int* ids = (const int*)d_in[1];
  const int* adj = (const int*)d_in[2];

  char* p = (char*)d_ws;
  auto alloc = [&](size_t bytes) {
    char* r = p;
    p += (bytes + 255) & ~(size_t)255;
    return r;
  };
  int* flag = (int*)alloc(256);
  // canonical bf16 params
  __hip_bfloat16* W1c = (__hip_bfloat16*)alloc((size_t)Hd * Hd * 2);
  __hip_bfloat16* W2c = (__hip_bfloat16*)alloc((size_t)Hd * Hd * 2);
  __hip_bfloat16* Wac = (__hip_bfloat16*)alloc((size_t)Hd * Hd * 2);
  __hip_bfloat16* Wlc = (__hip_bfloat16*)alloc((size_t)Hd * On * 2);
  __hip_bfloat16* b1c = (__hip_bfloat16*)alloc(Hd * 2);
  __hip_bfloat16* b2c = (__hip_bfloat16*)alloc(Hd * 2);
  __hip_bfloat16* bac = (__hip_bfloat16*)alloc(Hd * 2);
  __hip_bfloat16* blc = (__hip_bfloat16*)alloc(On * 2);
  __hip_bfloat16* a1c = (__hip_bfloat16*)alloc(2 * Hd * 2);
  __hip_bfloat16* a2c = (__hip_bfloat16*)alloc(2 * Hd * 2);
  __hip_bfloat16* vc  = (__hip_bfloat16*)alloc(Hd * 2);
  __hip_bfloat16* ab1c = (__hip_bfloat16*)alloc(256);
  __hip_bfloat16* ab2c = (__hip_bfloat16*)alloc(256);
  // intermediates
  float* xf = (float*)alloc((size_t)Bn * Nn * Hd * 4);
  __hip_bfloat16* xb = (__hip_bfloat16*)alloc((size_t)Bn * Nn * Hd * 2);
  __hip_bfloat16* Wt1 = (__hip_bfloat16*)alloc((size_t)Hd * Hd * 2);
  __hip_bfloat16* Wt2 = (__hip_bfloat16*)alloc((size_t)Hd * Hd * 2);
  __hip_bfloat16* Wta = (__hip_bfloat16*)alloc((size_t)Hd * Hd * 2);
  float* Wh = (float*)alloc((size_t)Bn * Nn * Hd * 4);
  float* att = (float*)alloc((size_t)Bn * Nn * Nn * 4);
  float* ssrc = (float*)alloc((size_t)Bn * Nn * 4);
  float* sdst = (float*)alloc((size_t)Bn * Nn * 4);
  __hip_bfloat16* hb = (__hip_bfloat16*)alloc((size_t)Bn * Nn * Hd * 2);
  float* h2f = (float*)alloc((size_t)Bn * Nn * Hd * 4);
  float* sraw = (float*)alloc((size_t)Bn * Nn * 4);
  __hip_bfloat16* db = (__hip_bfloat16*)alloc((size_t)Bn * Hd * 2);

  sniff_kernel<<<1, 256, 0, stream>>>((const unsigned int*)emb, flag);

  CvtJobs jobs;
  jobs.j[0]  = {d_in[3],  W1c, Hd * Hd, 0};
  jobs.j[1]  = {d_in[7],  W2c, Hd * Hd, 0};
  jobs.j[2]  = {d_in[11], Wac, Hd * Hd, 0};
  jobs.j[3]  = {d_in[14], Wlc, Hd * On, 0};
  jobs.j[4]  = {d_in[4],  b1c, Hd, 0};
  jobs.j[5]  = {d_in[8],  b2c, Hd, 0};
  jobs.j[6]  = {d_in[12], bac, Hd, 0};
  jobs.j[7]  = {d_in[15], blc, On, 0};
  jobs.j[8]  = {d_in[5],  a1c, 2 * Hd, 0};
  jobs.j[9]  = {d_in[9],  a2c, 2 * Hd, 0};
  jobs.j[10] = {d_in[13], vc,  Hd, 0};
  jobs.j[11] = {d_in[6],  ab1c, 1, 0};
  jobs.j[12] = {d_in[10], ab2c, 1, 0};
  cvt_kernel<<<dim3(64, 13), 256, 0, stream>>>(jobs, flag);

  dim3 tgrid(Hd / 32, Hd / 32);
  transpose_kernel<<<tgrid, 256, 0, stream>>>(W1c, Wt1);
  transpose_kernel<<<tgrid, 256, 0, stream>>>(W2c, Wt2);
  transpose_kernel<<<tgrid, 256, 0, stream>>>(Wac, Wta);

  gather_pe_kernel<<<Bn * Nn, 256, 0, stream>>>(emb, ids, flag, xf, xb);

  dim3 ggrid(Bn * Nn / 64, Hd / 64);  // 50 x 12
  // --- GAT layer 1 ---
  gemm_bt_kernel<0><<<ggrid, 256, 0, stream>>>(xb, Wt1, b1c, Wh);
  srcdst_kernel<<<Bn * Nn, 256, 0, stream>>>(Wh, a1c, ssrc, sdst);
  att_kernel<<<Bn * Nn, 64, 0, stream>>>(ssrc, sdst, adj, ab1c, att);
  attwh_kernel<1><<<Bn * Nn, 256, 0, stream>>>(att, Wh, nullptr, nullptr, hb);
  // --- GAT layer 2 (+ residual) ---
  gemm_bt_kernel<0><<<ggrid, 256, 0, stream>>>(hb, Wt2, b2c, Wh);
  srcdst_kernel<<<Bn * Nn, 256, 0, stream>>>(Wh, a2c, ssrc, sdst);
  att_kernel<<<Bn * Nn, 64, 0, stream>>>(ssrc, sdst, adj, ab2c, att);
  attwh_kernel<2><<<Bn * Nn, 256, 0, stream>>>(att, Wh, xf, h2f, hb);
  // --- attention pooling ---
  gemm_bt_kernel<1><<<ggrid, 256, 0, stream>>>(hb, Wta, bac, Wh);  // tanh(h@Wa+ba)
  dotv_kernel<<<Bn * Nn, 64, 0, stream>>>(Wh, vc, sraw);
  pool_kernel<<<Bn, 256, 0, stream>>>(sraw, h2f, db);
  // --- final linear ---
  final_kernel<<<dim3(Bn, On / 256), 256, 0, stream>>>(db, Wlc, blc, flag, out_size ? d_out : d_out);
}

// Round 3
// 313.325 us; speedup vs baseline: 1.1190x; 1.1190x over previous
//
#include <hip/hip_runtime.h>
#include <hip/hip_bf16.h>
#include <math.h>

typedef __attribute__((ext_vector_type(8))) short bf16x8;
typedef __attribute__((ext_vector_type(4))) float f32x4;

constexpr int Bn = 64;    // batch (dialogues)
constexpr int Ln = 512;   // utterances
constexpr int Hd = 768;   // hidden
constexpr int Nn = 50;    // nodes per dialogue
constexpr int On = 768;   // output dim

// ---------------------------------------------------------------------------
// prep: jobs 0..3 = cvt f32 -> bf16 + transpose (Wt[n][k] = W[k][n]) for
// W1, W2, Wa, Wl; job 4 = zero the atomic accumulator region.
struct PrepArgs {
  const float* src[4];
  __hip_bfloat16* dst[4];
  float* aux;
  int auxn;
};

__global__ __launch_bounds__(256) void prep_kernel(PrepArgs args) {
  int job = blockIdx.y;
  if (job < 4) {
    __shared__ float tile[32][33];
    int t = blockIdx.x;  // 0..575 (24x24 tiles of 32)
    int bx = (t % 24) * 32, by = (t / 24) * 32;
    const float* W = args.src[job];
    __hip_bfloat16* Wt = args.dst[job];
    int c = threadIdx.x & 31, r0 = threadIdx.x >> 5;
    for (int r = r0; r < 32; r += 8)
      tile[r][c] = W[(size_t)(bx + r) * Hd + by + c];
    __syncthreads();
    for (int r = r0; r < 32; r += 8)
      Wt[(size_t)(by + r) * Hd + bx + c] = __float2bfloat16(tile[c][r]);
  } else {
    int idx = blockIdx.x * 256 + threadIdx.x;
    if (idx < args.auxn) args.aux[idx] = 0.f;
  }
}

// ---------------------------------------------------------------------------
// Gather CLS rows + sinusoidal PE -> x (f32) and x (bf16). f32 input.
__global__ __launch_bounds__(256) void gather_pe_kernel(
    const float* __restrict__ emb, const int* __restrict__ ids,
    float* __restrict__ xf, __hip_bfloat16* __restrict__ xb) {
  int bn = blockIdx.x;  // b*Nn + n
  int b = bn / Nn, n = bn % Nn;
  int id = ids[bn];
  const float* src = emb + ((size_t)b * Ln + id) * Hd;
  float* xo = xf + (size_t)bn * Hd;
  __hip_bfloat16* xbo = xb + (size_t)bn * Hd;
  const float kLog = 9.210340371976184f / (float)Hd;  // ln(10000)/H
  for (int h = threadIdx.x; h < Hd; h += 256) {
    int he = h & ~1;
    float freq = expf(-(float)he * kLog);
    float ang = (float)n * freq;
    float pe = (h & 1) ? cosf(ang) : sinf(ang);
    float v = src[h] + pe;
    xo[h] = v;
    xbo[h] = __float2bfloat16(v);
  }
}

// ---------------------------------------------------------------------------
// C[M,768] = A[M,768] @ Bt[768,768]^T + bias.
// EPI 0: write C (f32) + fused src/dst attention dots:
//        atomicAdd(o1[row], C[row,:].avec[0:H]), atomicAdd(o2[row], .avec[H:2H])
// EPI 1: no C write; t = tanh(C+bias); atomicAdd(o1[row], t . avec[0:H])
template <int EPI>
__global__ __launch_bounds__(256) void gemm_kernel(
    const __hip_bfloat16* __restrict__ A, const __hip_bfloat16* __restrict__ Bt,
    const float* __restrict__ bias, float* __restrict__ C,
    const float* __restrict__ avec, float* __restrict__ o1,
    float* __restrict__ o2) {
  __shared__ __hip_bfloat16 As[64][40];  // pad to 40 (80B rows): conflict-free
  __shared__ __hip_bfloat16 Bs[64][40];
  int tid = threadIdx.x;
  int wave = tid >> 6, lane = tid & 63;
  int lr = lane & 15, lq = lane >> 4;
  int row0 = blockIdx.x * 64, col0 = blockIdx.y * 64;
  int sr = tid >> 2, sk = (tid & 3) * 8;
  const __hip_bfloat16* Ap = A + (size_t)(row0 + sr) * Hd + sk;
  const __hip_bfloat16* Bp = Bt + (size_t)(col0 + sr) * Hd + sk;
  f32x4 acc[4] = {};
  for (int kt = 0; kt < Hd; kt += 32) {
    *(uint4*)&As[sr][sk] = *(const uint4*)(Ap + kt);
    *(uint4*)&Bs[sr][sk] = *(const uint4*)(Bp + kt);
    __syncthreads();
    bf16x8 af = *(const bf16x8*)&As[wave * 16 + lr][lq * 8];
#pragma unroll
    for (int ct = 0; ct < 4; ++ct) {
      bf16x8 bfrag = *(const bf16x8*)&Bs[ct * 16 + lr][lq * 8];
      acc[ct] = __builtin_amdgcn_mfma_f32_16x16x32_bf16(af, bfrag, acc[ct], 0, 0, 0);
    }
    __syncthreads();
  }
  int cr0 = row0 + wave * 16 + lq * 4;
  if (EPI == 0) {
    float ps[4] = {}, pd[4] = {};
#pragma unroll
    for (int ct = 0; ct < 4; ++ct) {
      int gc = col0 + ct * 16 + lr;
      float bv = bias[gc];
      float as_ = avec[gc], ad_ = avec[Hd + gc];
#pragma unroll
      for (int r = 0; r < 4; ++r) {
        float v = acc[ct][r] + bv;
        C[(size_t)(cr0 + r) * Hd + gc] = v;
        ps[r] += v * as_;
        pd[r] += v * ad_;
      }
    }
#pragma unroll
    for (int off = 8; off; off >>= 1)
#pragma unroll
      for (int r = 0; r < 4; ++r) {
        ps[r] += __shfl_xor(ps[r], off);
        pd[r] += __shfl_xor(pd[r], off);
      }
    if (lr == 0)
#pragma unroll
      for (int r = 0; r < 4; ++r) {
        atomicAdd(&o1[cr0 + r], ps[r]);
        atomicAdd(&o2[cr0 + r], pd[r]);
      }
  } else {
    float pr[4] = {};
#pragma unroll
    for (int ct = 0; ct < 4; ++ct) {
      int gc = col0 + ct * 16 + lr;
      float bv = bias[gc];
      float vv_ = avec[gc];
#pragma unroll
      for (int r = 0; r < 4; ++r) {
        float t = tanhf(acc[ct][r] + bv);
        pr[r] += t * vv_;
      }
    }
#pragma unroll
    for (int off = 8; off; off >>= 1)
#pragma unroll
      for (int r = 0; r < 4; ++r) pr[r] += __shfl_xor(pr[r], off);
    if (lr == 0)
#pragma unroll
      for (int r = 0; r < 4; ++r) atomicAdd(&o1[cr0 + r], pr[r]);
  }
}

// ---------------------------------------------------------------------------
// Fused attention: block = (h-chunk of 128, dialogue b).
// Build att = softmax(mask(adj, leaky_relu(ssrc_i + sdst_j + ab))) in LDS,
// then out[i, h0+col] = elu(sum_j att[i][j] * Wh[b][j][h0+col]) (+residual L2).
template <int LAYER>
__global__ __launch_bounds__(256) void attf_kernel(
    const float* __restrict__ ssrc, const float* __restrict__ sdst,
    const int* __restrict__ adj, const float* __restrict__ ab,
    const float* __restrict__ Wh, const float* __restrict__ xres,
    float* __restrict__ hf, __hip_bfloat16* __restrict__ hb) {
  int b = blockIdx.y, h0 = blockIdx.x * 128;
  __shared__ float attL[Nn * Nn];
  float abv = ab[0];
  for (int idx = threadIdx.x; idx < Nn * Nn; idx += 256) {
    int i = idx / Nn, j = idx - i * Nn;
    float t = ssrc[b * Nn + i] + sdst[b * Nn + j] + abv;
    t = t > 0.f ? t : 0.3f * t;  // leaky_relu alpha=0.3
    attL[idx] = (adj[(size_t)b * Nn * Nn + idx] > 0) ? t : -9.0e15f;
  }
  __syncthreads();
  if (threadIdx.x < Nn) {  // per-row softmax, serial over 50 cols
    int i = threadIdx.x;
    float m = -3.0e38f;
    for (int j = 0; j < Nn; ++j) m = fmaxf(m, attL[i * Nn + j]);
    float s = 0.f;
    for (int j = 0; j < Nn; ++j) {
      float p = expf(attL[i * Nn + j] - m);
      attL[i * Nn + j] = p;
      s += p;
    }
    float inv = 1.f / s;
    for (int j = 0; j < Nn; ++j) attL[i * Nn + j] *= inv;
  }
  __syncthreads();
  int col = threadIdx.x & 127, half = threadIdx.x >> 7;
  int i0 = half * 25;
  float acc[25] = {};
  const float* Whb = Wh + ((size_t)b * Nn) * Hd + h0 + col;
  for (int j = 0; j < Nn; j += 2) {
    float w0 = Whb[(size_t)j * Hd];
    float w1 = Whb[(size_t)(j + 1) * Hd];
#pragma unroll
    for (int ii = 0; ii < 25; ++ii) {
      float2 a2 = *(const float2*)&attL[(i0 + ii) * Nn + j];
      acc[ii] += a2.x * w0 + a2.y * w1;
    }
  }
#pragma unroll
  for (int ii = 0; ii < 25; ++ii) {
    float v = acc[ii];
    v = v > 0.f ? v : expf(v) - 1.f;  // elu
    size_t off = ((size_t)b * Nn + i0 + ii) * Hd + h0 + col;
    if (LAYER == 2) {
      v += xres[off];
      hf[off] = v;
    }
    hb[off] = __float2bfloat16(v);
  }
}

// ---------------------------------------------------------------------------
// Fused pooling + final linear. Block per dialogue b.
// sc = softmax(sraw[b]); d = sc @ h2[b]; out[b,:] = d @ Wlt^T + bl.
__global__ __launch_bounds__(256) void poolfinal_kernel(
    const float* __restrict__ sraw, const float* __restrict__ h2,
    const __hip_bfloat16* __restrict__ Wlt, const float* __restrict__ bl,
    float* __restrict__ out) {
  int b = blockIdx.x;
  __shared__ float sc[Nn];
  __shared__ float ds[Hd];
  if (threadIdx.x < 64) {
    int j = threadIdx.x;
    float e = (j < Nn) ? sraw[b * Nn + j] : -3.0e38f;
    float m = e;
#pragma unroll
    for (int off = 32; off; off >>= 1) m = fmaxf(m, __shfl_xor(m, off));
    float p = (j < Nn) ? expf(e - m) : 0.f;
    float s = p;
#pragma unroll
    for (int off = 32; off; off >>= 1) s += __shfl_xor(s, off);
    if (j < Nn) sc[j] = p / s;
  }
  __syncthreads();
  for (int h = threadIdx.x; h < Hd; h += 256) {
    float a = 0.f;
#pragma unroll 10
    for (int j = 0; j < Nn; ++j) a += sc[j] * h2[((size_t)b * Nn + j) * Hd + h];
    ds[h] = a;
  }
  __syncthreads();
  for (int oo = 0; oo < 3; ++oo) {
    int o = oo * 256 + threadIdx.x;
    float acc = bl[o];
    const uint4* wr = (const uint4*)(Wlt + (size_t)o * Hd);
    for (int kk = 0; kk < Hd / 8; ++kk) {
      union { uint4 u; unsigned short s[8]; } w;
      w.u = wr[kk];
#pragma unroll
      for (int t = 0; t < 8; ++t)
        acc += ds[kk * 8 + t] * __uint_as_float((unsigned)w.s[t] << 16);
    }
    out[(size_t)b * On + o] = acc;
  }
}

// ---------------------------------------------------------------------------
extern "C" void kernel_launch(void* const* d_in, const int* in_sizes, int n_in,
                              void* d_out, int out_size, void* d_ws, size_t ws_size,
                              hipStream_t stream) {
  const float* emb = (const float*)d_in[0];
  const int* ids = (const int*)d_in[1];
  const int* adj = (const int*)d_in[2];
  const float* W1 = (const float*)d_in[3];
  const float* b1 = (const float*)d_in[4];
  const float* a1 = (const float*)d_in[5];
  const float* ab1 = (const float*)d_in[6];
  const float* W2 = (const float*)d_in[7];
  const float* b2 = (const float*)d_in[8];
  const float* a2 = (const float*)d_in[9];
  const float* ab2 = (const float*)d_in[10];
  const float* Wa = (const float*)d_in[11];
  const float* ba = (const float*)d_in[12];
  const float* vv = (const float*)d_in[13];
  const float* Wl = (const float*)d_in[14];
  const float* bl = (const float*)d_in[15];
  float* out = (float*)d_out;

  char* p = (char*)d_ws;
  auto alloc = [&](size_t bytes) {
    char* r = p;
    p += (bytes + 255) & ~(size_t)255;
    return r;
  };
  __hip_bfloat16* Wt1 = (__hip_bfloat16*)alloc((size_t)Hd * Hd * 2);
  __hip_bfloat16* Wt2 = (__hip_bfloat16*)alloc((size_t)Hd * Hd * 2);
  __hip_bfloat16* Wta = (__hip_bfloat16*)alloc((size_t)Hd * Hd * 2);
  __hip_bfloat16* Wlt = (__hip_bfloat16*)alloc((size_t)Hd * On * 2);
  float* aux = (float*)alloc(5 * Bn * Nn * 4);  // ssrc1,sdst1,ssrc2,sdst2,sraw
  float* ssrc1 = aux;
  float* sdst1 = aux + Bn * Nn;
  float* ssrc2 = aux + 2 * Bn * Nn;
  float* sdst2 = aux + 3 * Bn * Nn;
  float* sraw = aux + 4 * Bn * Nn;
  float* xf = (float*)alloc((size_t)Bn * Nn * Hd * 4);
  __hip_bfloat16* xb = (__hip_bfloat16*)alloc((size_t)Bn * Nn * Hd * 2);
  float* Wh = (float*)alloc((size_t)Bn * Nn * Hd * 4);
  float* h2f = (float*)alloc((size_t)Bn * Nn * Hd * 4);
  __hip_bfloat16* hb = (__hip_bfloat16*)alloc((size_t)Bn * Nn * Hd * 2);

  PrepArgs pa;
  pa.src[0] = W1; pa.src[1] = W2; pa.src[2] = Wa; pa.src[3] = Wl;
  pa.dst[0] = Wt1; pa.dst[1] = Wt2; pa.dst[2] = Wta; pa.dst[3] = Wlt;
  pa.aux = aux; pa.auxn = 5 * Bn * Nn;
  prep_kernel<<<dim3(576, 5), 256, 0, stream>>>(pa);

  gather_pe_kernel<<<Bn * Nn, 256, 0, stream>>>(emb, ids, xf, xb);

  dim3 ggrid(Bn * Nn / 64, Hd / 64);  // 50 x 12
  dim3 agrid(Hd / 128, Bn);           // 6 x 64

  // --- GAT layer 1 ---
  gemm_kernel<0><<<ggrid, 256, 0, stream>>>(xb, Wt1, b1, Wh, a1, ssrc1, sdst1);
  attf_kernel<1><<<agrid, 256, 0, stream>>>(ssrc1, sdst1, adj, ab1, Wh,
                                            nullptr, nullptr, hb);
  // --- GAT layer 2 (+ residual) ---
  gemm_kernel<0><<<ggrid, 256, 0, stream>>>(hb, Wt2, b2, Wh, a2, ssrc2, sdst2);
  attf_kernel<2><<<agrid, 256, 0, stream>>>(ssrc2, sdst2, adj, ab2, Wh,
                                            xf, h2f, hb);
  // --- attention pooling scores: sraw[row] = tanh(h2@Wa+ba) . v ---
  gemm_kernel<1><<<ggrid, 256, 0, stream>>>(hb, Wta, ba, nullptr, vv, sraw,
                                            nullptr);
  // --- pool + final linear ---
  poolfinal_kernel<<<Bn, 256, 0, stream>>>(sraw, h2f, Wlt, bl, out);
}